// Round 3
// baseline (238.605 us; speedup 1.0000x reference)
//
#include <hip/hip_runtime.h>
#include <math.h>

#define NATOMS    128
#define NSEG      7875     // segments: i in [0,124], j in [i+2,126]
#define NSEG_PAD  8192     // swr padded; pad entries written but never read
#define NPAIR     8128     // pairs (a,b), 0 <= a < b <= 127
#define OUT_PER_B 16256    // 128*127 (row-major, diagonal skipped)
#define BLOCK     512
#define NCHUNK    2048     // 2048 chunks x 4 segments = 8192 (>= NSEG)

typedef float v2f __attribute__((ext_vector_type(2)));
typedef float v4f __attribute__((ext_vector_type(4)));   // clang vector: OK for nontemporal builtins
__device__ __forceinline__ v2f mk2(float a, float b) { v2f r; r.x = a; r.y = b; return r; }

struct P3 { v2f x, y, z; };
__device__ __forceinline__ P3 psub(P3 a, P3 b) { return {a.x - b.x, a.y - b.y, a.z - b.z}; }
__device__ __forceinline__ P3 pcross(P3 a, P3 b) {
    return {a.y * b.z - a.z * b.y, a.z * b.x - a.x * b.z, a.x * b.y - a.y * b.x};
}
__device__ __forceinline__ v2f pdot(P3 a, P3 b) { return a.x * b.x + a.y * b.y + a.z * b.z; }
__device__ __forceinline__ v2f prsq(v2f q) {
    v2f r; r.x = __builtin_amdgcn_rsqf(q.x); r.y = __builtin_amdgcn_rsqf(q.y); return r;
}
__device__ __forceinline__ v2f pclip1(v2f x) {
    return __builtin_elementwise_min(__builtin_elementwise_max(x, mk2(-1.f, -1.f)),
                                     mk2(1.f, 1.f));
}

// Packed 4-term branchless asin, A&S 4.4.45 (|err| <= 6.8e-5).
__device__ __forceinline__ v2f fast_asin2(v2f x) {
    v2f a = __builtin_elementwise_abs(x);
    v2f p = mk2(-0.0187293f, -0.0187293f);
    p = p * a + mk2( 0.0742610f,  0.0742610f);
    p = p * a + mk2(-0.2121144f, -0.2121144f);
    p = p * a + mk2( 1.5707288f,  1.5707288f);
    v2f om = mk2(1.0f, 1.0f) - a;
    v2f sq; sq.x = __builtin_amdgcn_sqrtf(om.x); sq.y = __builtin_amdgcn_sqrtf(om.y);
    v2f r = mk2(1.57079632679f, 1.57079632679f) - sq * p;
    return __builtin_elementwise_copysign(r, x);
}

__device__ __forceinline__ int seg_row_base(int i) { return 125 * i - (__umul24(i, i - 1) >> 1); }

// (i,j) from linear segment id s (sqrt seed + exact fixup); s must be < NSEG.
__device__ __forceinline__ void seed_ij(int s, int &i, int &j) {
    i = (int)((251.0f - __builtin_amdgcn_sqrtf(63001.0f - 8.0f * (float)s)) * 0.5f);
    i = max(i, 0);
    i += (seg_row_base(i + 1) <= s);
    i += (seg_row_base(i + 1) <= s);
    i -= (seg_row_base(i) > s);
    i -= (seg_row_base(i) > s);
    j = s - seg_row_base(i) + i + 2;
}

// Advance (i,j) to the next row-major segment; clamp at the last real segment
// (124,126) so pad chunks keep re-processing a valid segment. Returns "row crossed".
__device__ __forceinline__ bool adv(int &i, int &j) {
    ++j;
    bool c = (j > 126);
    int i2 = i + 1;
    bool over = (i2 > 124);
    int ni = over ? 124 : i2;
    int nj = over ? 126 : (i2 + 2);
    i = c ? ni : i;
    j = c ? nj : j;
    return c;
}

__device__ __forceinline__ P3 pack3(const float4 &a, const float4 &b) {
    return { mk2(a.x, b.x), mk2(a.y, b.y), mk2(a.z, b.z) };
}
__device__ __forceinline__ v2f sel2(v2f o, v2f n, bool cA, bool cB) {
    v2f r; r.x = cA ? n.x : o.x; r.y = cB ? n.y : o.y; return r;
}
__device__ __forceinline__ P3 sel3(P3 o, P3 n, bool cA, bool cB) {
    return { sel2(o.x, n.x, cA, cB), sel2(o.y, n.y, cA, cB), sel2(o.z, n.z, cA, cB) };
}

// ---- Sliding-window writhe chain (2 packed sub-lanes walk 2 row-chunks) ----
// Carried state across steps for segment (i,j) -> (i,j+1):
//   u0' = u1, u2' = u3, n3' = -n1, q3' = q1  (exact identities)
// so each step loads ONE new point (atom j+1) per sub-lane, computes 3 crosses.
struct Chain {
    P3 p0, p1;            // atoms i, i+1 (per sub-lane, packed)
    P3 u1p, u3p, n1p;     // previous u1, u3, n1
    v2f q1p;              // previous |n1|^2
    int iA, jA, iB, jB;
};

__device__ __forceinline__ void chain_init(Chain &ch, int sA, int sB, const float4 *sp4) {
    seed_ij(min(sA, NSEG - 1), ch.iA, ch.jA);
    seed_ij(min(sB, NSEG - 1), ch.iB, ch.jB);
    float4 a0 = sp4[ch.iA], a1 = sp4[ch.iA + 1], a2 = sp4[ch.jA];
    float4 b0 = sp4[ch.iB], b1 = sp4[ch.iB + 1], b2 = sp4[ch.jB];
    ch.p0 = pack3(a0, b0); ch.p1 = pack3(a1, b1);
    P3 p2 = pack3(a2, b2);
    ch.u1p = psub(p2, ch.p0);     // == u0 of first segment
    ch.u3p = psub(p2, ch.p1);     // == u2 of first segment
    ch.n1p = pcross(ch.u1p, ch.u3p);   // n3 = -n1p (= u2 x u0)
    ch.q1p = pdot(ch.n1p, ch.n1p);
}

__device__ __forceinline__ void chain_advance(Chain &ch, const float4 *sp4) {
    bool cA = adv(ch.iA, ch.jA);
    bool cB = adv(ch.iB, ch.jB);
    if (cA || cB) {   // row crossing: rebuild state for crossed sub-lane(s) only
        float4 a0 = sp4[ch.iA], a1 = sp4[ch.iA + 1], a2 = sp4[ch.jA];
        float4 b0 = sp4[ch.iB], b1 = sp4[ch.iB + 1], b2 = sp4[ch.jB];
        P3 np0 = pack3(a0, b0), np1 = pack3(a1, b1), np2 = pack3(a2, b2);
        P3 nu1 = psub(np2, np0), nu3 = psub(np2, np1);
        P3 nn1 = pcross(nu1, nu3);
        v2f nq1 = pdot(nn1, nn1);
        ch.p0  = sel3(ch.p0,  np0, cA, cB);
        ch.p1  = sel3(ch.p1,  np1, cA, cB);
        ch.u1p = sel3(ch.u1p, nu1, cA, cB);
        ch.u3p = sel3(ch.u3p, nu3, cA, cB);
        ch.n1p = sel3(ch.n1p, nn1, cA, cB);
        ch.q1p = sel2(ch.q1p, nq1, cA, cB);
    }
}

__device__ __forceinline__ v2f chain_step(Chain &ch, const float4 *sp4) {
    float4 a3 = sp4[ch.jA + 1];
    float4 b3 = sp4[ch.jB + 1];
    P3 p3 = pack3(a3, b3);
    P3 u1 = psub(p3, ch.p0);
    P3 u3 = psub(p3, ch.p1);
    P3 n0 = pcross(ch.u1p, u1);        // u0 x u1
    P3 n1 = pcross(u1, u3);
    P3 n2 = pcross(u3, ch.u3p);        // u3 x u2
    v2f q0 = pdot(n0, n0), q1 = pdot(n1, n1), q2 = pdot(n2, n2);
    v2f d01 = pdot(n0, n1), d12 = pdot(n1, n2);
    v2f d23 = pdot(n2, ch.n1p);        // dot(n2,n3) = -d23
    v2f d30 = pdot(ch.n1p, n0);        // dot(n3,n0) = -d30
    v2f sd  = pdot(n2, ch.u1p);        // dot(n2,u0) (sign folded as before)
    v2f c0 = pclip1(d01 * prsq(q0 * q1));
    v2f c1 = pclip1(d12 * prsq(q1 * q2));
    v2f c2 = pclip1((-d23) * prsq(q2 * ch.q1p));   // q3 = q1p
    v2f c3 = pclip1((-d30) * prsq(ch.q1p * q0));
    v2f omega = fast_asin2(c0) + fast_asin2(c1) + fast_asin2(c2) + fast_asin2(c3);
    v2f sgn;
    sgn.x = (sd.x > 0.f) ? -1.f : ((sd.x < 0.f) ? 1.f : 0.f);
    sgn.y = (sd.y > 0.f) ? -1.f : ((sd.y < 0.f) ? 1.f : 0.f);
    ch.u1p = u1; ch.u3p = u3; ch.n1p = n1; ch.q1p = q1;   // slide window
    return omega * sgn * mk2(0.15915494309189535f, 0.15915494309189535f);
}

// One block per batch.
// Phase A: sliding-window row-walk. 2048 chunks x 4 row-major segments;
//          thread t owns chunks {t, t+512} (chain0 packed lanes) and
//          {t+1024, t+1536} (chain1). Per segment: 1 ds_read_b128/sub-lane
//          (vs 24 ds_read_b32 per packed pair before), 3 crosses (vs 4).
//          sidx table deleted (indices computed in-register).
// Phase D: row-major gather + coalesced nontemporal float4 store (verified r1).
// LDS: sp4 2K + swr 32K ~= 34.3 KB; lb(512,4) -> VGPR cap 128, 2 blocks/CU.
__global__ __launch_bounds__(BLOCK, 4) void writhe_fused(
    const float* __restrict__ xyz,       // (B, 128, 3)
    float*       __restrict__ out)       // (B, 16256)
{
    __shared__ float4 sp4[NATOMS];
    __shared__ float  swr[NSEG_PAD];

    const int b = blockIdx.x;
    const int t = threadIdx.x;

    if (t < 3 * NATOMS) {
        float v = xyz[(size_t)b * (3 * NATOMS) + t];
        int a = t / 3, c = t - 3 * a;
        ((float*)&sp4[a])[c] = v;
    }
    __syncthreads();

    // ---------- Phase A ----------
    {
        Chain c0, c1;
        chain_init(c0, 4 * t,          4 * (t + 512),  sp4);
        chain_init(c1, 4 * (t + 1024), 4 * (t + 1536), sp4);

        v2f wA[4], wB[4];
        #pragma unroll
        for (int k = 0; k < 4; ++k) {
            if (k) { chain_advance(c0, sp4); chain_advance(c1, sp4); }
            wA[k] = chain_step(c0, sp4);
            wB[k] = chain_step(c1, sp4);
        }

        v4f r;
        r.x = wA[0].x; r.y = wA[1].x; r.z = wA[2].x; r.w = wA[3].x;
        *reinterpret_cast<v4f*>(swr + 4 * t)          = r;
        r.x = wA[0].y; r.y = wA[1].y; r.z = wA[2].y; r.w = wA[3].y;
        *reinterpret_cast<v4f*>(swr + 4 * t + 2048)   = r;
        r.x = wB[0].x; r.y = wB[1].x; r.z = wB[2].x; r.w = wB[3].x;
        *reinterpret_cast<v4f*>(swr + 4 * t + 4096)   = r;
        r.x = wB[0].y; r.y = wB[1].y; r.z = wB[2].y; r.w = wB[3].y;
        *reinterpret_cast<v4f*>(swr + 4 * t + 6144)   = r;
    }
    __syncthreads();

    // ---------- Phase D: row-major gather + coalesced float4 store ----------
    // k in [0, 16256): r = k/127 (exact magic mul), c' = k%127, c = c' + (c'>=r).
    float* ob = out + (size_t)b * OUT_PER_B;
    for (int kq = t; kq < OUT_PER_B / 4; kq += BLOCK) {
        const int k0 = kq << 2;
        float acc[4];
        #pragma unroll
        for (int q = 0; q < 4; ++q) {
            const int k = k0 + q;
            const int r = (int)(((unsigned)k * 132105u) >> 24);
            int c = k - r * 127;
            c += (c >= r);
            const int a  = min(r, c);
            const int bb = max(r, c);

            const int am1 = a - 1;
            const int s00 = 125 * am1 - ((am1 * (am1 - 1)) >> 1) + bb - a - 2;  // (a-1, b-1)
            const int s10 = s00 + 125 - a;                                      // (a,   b-1)

            const bool v00 = (a >= 1) && (a <= 125) && (bb >= a + 2);
            const bool v01 = (a >= 1) && (a <= 125) && (bb <= 126);
            const bool v10 = (a <= 124) && (bb >= a + 3);
            const bool v11 = (a <= 124) && (bb <= 126) && (bb >= a + 2);

            const int c00 = min(max(s00,     0), NSEG - 1);
            const int c01 = min(max(s00 + 1, 0), NSEG - 1);
            const int c10 = min(max(s10,     0), NSEG - 1);
            const int c11 = min(max(s10 + 1, 0), NSEG - 1);

            acc[q] = (v00 ? swr[c00] : 0.0f) + (v01 ? swr[c01] : 0.0f)
                   + (v10 ? swr[c10] : 0.0f) + (v11 ? swr[c11] : 0.0f);
        }
        v4f res; res.x = acc[0]; res.y = acc[1]; res.z = acc[2]; res.w = acc[3];
        __builtin_nontemporal_store(res, reinterpret_cast<v4f*>(ob + k0));
    }
}

extern "C" void kernel_launch(void* const* d_in, const int* in_sizes, int n_in,
                              void* d_out, int out_size, void* d_ws, size_t ws_size,
                              hipStream_t stream) {
    const float* xyz = (const float*)d_in[0];
    float*       out = (float*)d_out;

    int B = in_sizes[0] / (NATOMS * 3);   // 512 for the reference shapes
    writhe_fused<<<B, BLOCK, 0, stream>>>(xyz, out);
}

// Round 4
// 92.279 us; speedup vs baseline: 2.5857x; 2.5857x over previous
//
#include <hip/hip_runtime.h>
#include <math.h>

#define NATOMS    128
#define NSEG      7875     // segments: i in [0,124], j in [i+2,126]
#define NSEG_PAD  8192     // padded so Phase A needs no predication
#define NPAIR     8128     // pairs (a,b), 0 <= a < b <= 127
#define OUT_PER_B 16256    // 128*127 (row-major, diagonal skipped)
#define BLOCK     512

typedef float v2f __attribute__((ext_vector_type(2)));
__device__ __forceinline__ v2f mk2(float a, float b) { v2f r; r.x = a; r.y = b; return r; }

struct P3 { v2f x, y, z; };
__device__ __forceinline__ P3 psub(P3 a, P3 b) { return {a.x - b.x, a.y - b.y, a.z - b.z}; }
__device__ __forceinline__ P3 pcross(P3 a, P3 b) {
    return {a.y * b.z - a.z * b.y, a.z * b.x - a.x * b.z, a.x * b.y - a.y * b.x};
}
__device__ __forceinline__ v2f pdot(P3 a, P3 b) { return a.x * b.x + a.y * b.y + a.z * b.z; }
__device__ __forceinline__ v2f prsq(v2f q) {
    v2f r; r.x = __builtin_amdgcn_rsqf(q.x); r.y = __builtin_amdgcn_rsqf(q.y); return r;
}
__device__ __forceinline__ v2f pclip1(v2f x) {
    return __builtin_elementwise_min(__builtin_elementwise_max(x, mk2(-1.f, -1.f)),
                                     mk2(1.f, 1.f));
}

// Packed 4-term branchless asin, A&S 4.4.45 (|err| <= 6.8e-5).
__device__ __forceinline__ v2f fast_asin2(v2f x) {
    v2f a = __builtin_elementwise_abs(x);
    v2f p = mk2(-0.0187293f, -0.0187293f);
    p = p * a + mk2( 0.0742610f,  0.0742610f);
    p = p * a + mk2(-0.2121144f, -0.2121144f);
    p = p * a + mk2( 1.5707288f,  1.5707288f);
    v2f om = mk2(1.0f, 1.0f) - a;
    v2f sq; sq.x = __builtin_amdgcn_sqrtf(om.x); sq.y = __builtin_amdgcn_sqrtf(om.y);
    v2f r = mk2(1.57079632679f, 1.57079632679f) - sq * p;
    return __builtin_elementwise_copysign(r, x);
}

__device__ __forceinline__ int seg_row_base(int i) { return 125 * i - (__umul24(i, i - 1) >> 1); }

__device__ __forceinline__ P3 pack3(const float4 &a, const float4 &b) {
    return { mk2(a.x, b.x), mk2(a.y, b.y), mk2(a.z, b.z) };
}

// Writhe for TWO packed segments (x-lane = pa, y-lane = pb). Coordinates come
// from float4 LDS (1 ds_read_b128 per point per sub-lane = 8 loads total, vs
// 24 scalar ds_read_b32 in the previous layout). Sign via the exact identity
//   cross(p3-p2, p1-p0) . u0 = -(u3 x u2) . u0 = -n2 . u0.
__device__ __forceinline__ v2f seg_writhe_pair(unsigned pa, unsigned pb,
                                               const float4* sp4) {
    int jA = (int)(pa & 127u), iA = (int)(pa >> 7);
    int jB = (int)(pb & 127u), iB = (int)(pb >> 7);

    float4 A0 = sp4[iA], A1 = sp4[iA + 1], A2 = sp4[jA], A3 = sp4[jA + 1];
    float4 B0 = sp4[iB], B1 = sp4[iB + 1], B2 = sp4[jB], B3 = sp4[jB + 1];

    P3 p0 = pack3(A0, B0);
    P3 p1 = pack3(A1, B1);
    P3 p2 = pack3(A2, B2);
    P3 p3 = pack3(A3, B3);

    P3 u0 = psub(p2, p0);
    P3 u1 = psub(p3, p0);
    P3 u2 = psub(p2, p1);
    P3 u3 = psub(p3, p1);

    P3 n0 = pcross(u0, u1);
    P3 n1 = pcross(u1, u3);
    P3 n2 = pcross(u3, u2);
    P3 n3 = pcross(u2, u0);

    v2f q0 = pdot(n0, n0);
    v2f q1 = pdot(n1, n1);
    v2f q2 = pdot(n2, n2);
    v2f q3 = pdot(n3, n3);

    v2f c0 = pclip1(pdot(n0, n1) * prsq(q0 * q1));
    v2f c1 = pclip1(pdot(n1, n2) * prsq(q1 * q2));
    v2f c2 = pclip1(pdot(n2, n3) * prsq(q2 * q3));
    v2f c3 = pclip1(pdot(n3, n0) * prsq(q3 * q0));

    v2f sd = pdot(n2, u0);     // = -(reference sd); sign folded below
    v2f omega = fast_asin2(c0) + fast_asin2(c1) + fast_asin2(c2) + fast_asin2(c3);

    v2f sgn;
    sgn.x = (sd.x > 0.f) ? -1.f : ((sd.x < 0.f) ? 1.f : 0.f);
    sgn.y = (sd.y > 0.f) ? -1.f : ((sd.y < 0.f) ? 1.f : 0.f);

    return omega * sgn * mk2(0.15915494309189535f, 0.15915494309189535f);
}

// One block per batch.
// Phase 0: u16 segment index table (sidx, padded to 8192).
// Phase A: packed-pair writhe -> swr. 2 independent packed chains x 4
//          iterations = 16 segments/thread. Coords via float4 LDS (b128).
// Phase D: k = t + q*BLOCK mapping: gathers are stride-1 across lanes
//          (upper-triangle rows conflict-free; old 4t+q mapping was 8-way
//          conflicted on EVERY gather -- 3.4M conflict cycles measured),
//          stores scalar but perfectly coalesced + nontemporal.
// No carried state across segments (round-3 sliding window spilled ~1KB/thread
// to scratch: 183MB FETCH / 299MB WRITE, 184us. This structure measured clean).
// LDS: sp4 2K + swr 32K + sidx 16K ~= 50.3 KB; lb(512,4): VGPR cap 128, 2 blk/CU.
__global__ __launch_bounds__(BLOCK, 4) void writhe_fused(
    const float* __restrict__ xyz,       // (B, 128, 3)
    float*       __restrict__ out)       // (B, 16256)
{
    __shared__ float4 sp4[NATOMS];
    __shared__ float  swr[NSEG_PAD];
    __shared__ unsigned short sidx[NSEG_PAD];

    const int b = blockIdx.x;
    const int t = threadIdx.x;

    if (t < 3 * NATOMS) {
        float v = xyz[(size_t)b * (3 * NATOMS) + t];
        int a = t / 3, c = t - 3 * a;
        ((float*)&sp4[a])[c] = v;
    }

    // ---------- Phase 0: build sidx (+ pad tail with a safe segment) ----------
    {
        int s = t * 16;
        if (s < NSEG) {
            int i = (int)((251.0f - __builtin_amdgcn_sqrtf(63001.0f - 8.0f * (float)s)) * 0.5f);
            i = max(i, 0);
            i += (seg_row_base(i + 1) <= s);
            i += (seg_row_base(i + 1) <= s);
            i -= (seg_row_base(i) > s);
            i -= (seg_row_base(i) > s);
            int j = s - seg_row_base(i) + i + 2;
            #pragma unroll
            for (int k = 0; k < 16; ++k) {
                if (s < NSEG) sidx[s] = (unsigned short)((i << 7) | j);
                ++s; ++j;
                if (j > 126) { ++i; j = i + 2; }
            }
        }
        if (t < NSEG_PAD - NSEG) sidx[NSEG + t] = (unsigned short)((124 << 7) | 126);
    }
    __syncthreads();

    // ---------- Phase A: packed-pair writhe, 2 chains x 4 iterations ----------
    #pragma unroll
    for (int g = 0; g < 4; ++g) {
        const int sA = g * 2048 + t;     // sA..sA+1536 < 8192: unconditional
        v2f w1 = seg_writhe_pair(sidx[sA],        sidx[sA + 512],  sp4);
        v2f w2 = seg_writhe_pair(sidx[sA + 1024], sidx[sA + 1536], sp4);
        swr[sA]        = w1.x;
        swr[sA + 512]  = w1.y;
        swr[sA + 1024] = w2.x;
        swr[sA + 1536] = w2.y;
    }
    __syncthreads();

    // ---------- Phase D: lane-consecutive gather + coalesced store ----------
    // k in [0, 16256): r = k/127 (exact magic mul), c' = k%127, c = c' + (c'>=r).
    // Lane l handles k = l + q*BLOCK: each gather instruction sees stride-1
    // swr addresses across lanes (<=2 lanes/bank = conflict-free).
    float* ob = out + (size_t)b * OUT_PER_B;
    for (int k = t; k < OUT_PER_B; k += BLOCK) {
        const int r = (int)(((unsigned)k * 132105u) >> 24);
        int c = k - r * 127;
        c += (c >= r);
        const int a  = min(r, c);
        const int bb = max(r, c);

        // segment ids for (i,j) in {a-1,a} x {b-1,b}; s(i,j)=base(i)+j-i-2
        const int am1 = a - 1;
        const int s00 = 125 * am1 - ((am1 * (am1 - 1)) >> 1) + bb - a - 2;  // (a-1, b-1)
        const int s10 = s00 + 125 - a;                                      // (a,   b-1)

        const bool v00 = (a >= 1) && (a <= 125) && (bb >= a + 2);
        const bool v01 = (a >= 1) && (a <= 125) && (bb <= 126);
        const bool v10 = (a <= 124) && (bb >= a + 3);
        const bool v11 = (a <= 124) && (bb <= 126) && (bb >= a + 2);

        const int c00 = min(max(s00,     0), NSEG - 1);
        const int c01 = min(max(s00 + 1, 0), NSEG - 1);
        const int c10 = min(max(s10,     0), NSEG - 1);
        const int c11 = min(max(s10 + 1, 0), NSEG - 1);

        float sum = (v00 ? swr[c00] : 0.0f) + (v01 ? swr[c01] : 0.0f)
                  + (v10 ? swr[c10] : 0.0f) + (v11 ? swr[c11] : 0.0f);

        __builtin_nontemporal_store(sum, ob + k);
    }
}

extern "C" void kernel_launch(void* const* d_in, const int* in_sizes, int n_in,
                              void* d_out, int out_size, void* d_ws, size_t ws_size,
                              hipStream_t stream) {
    const float* xyz = (const float*)d_in[0];
    float*       out = (float*)d_out;

    int B = in_sizes[0] / (NATOMS * 3);   // 512 for the reference shapes
    writhe_fused<<<B, BLOCK, 0, stream>>>(xyz, out);
}